// Round 11
// baseline (1506.190 us; speedup 1.0000x reference)
//
#include <hip/hip_runtime.h>
#include <math.h>

#define HIDDEN 512
#define INPUT  64
#define NB     64     // distinct batch rows (8 trials are bit-identical replicas)
#define NT     8
#define WARM   100
#define RESP   400
#define STEPS  (WARM + RESP)
#define ALPHA  0.1f

typedef _Float16 half8 __attribute__((ext_vector_type(8)));

#if defined(__has_builtin)
#  if __has_builtin(__builtin_amdgcn_fdot2)
#    define HAS_FDOT2 1
#  endif
#endif

__device__ __forceinline__ void dot8(half8 w, half8 s, float& a0, float& a1) {
#ifdef HAS_FDOT2
  a0 = __builtin_amdgcn_fdot2(__builtin_shufflevector(w, w, 0, 1),
                              __builtin_shufflevector(s, s, 0, 1), a0, false);
  a1 = __builtin_amdgcn_fdot2(__builtin_shufflevector(w, w, 2, 3),
                              __builtin_shufflevector(s, s, 2, 3), a1, false);
  a0 = __builtin_amdgcn_fdot2(__builtin_shufflevector(w, w, 4, 5),
                              __builtin_shufflevector(s, s, 4, 5), a0, false);
  a1 = __builtin_amdgcn_fdot2(__builtin_shufflevector(w, w, 6, 7),
                              __builtin_shufflevector(s, s, 6, 7), a1, false);
#else
#pragma unroll
  for (int l = 0; l < 8; ++l)
    ((l & 1) ? a1 : a0) = fmaf((float)w[l], (float)s[l], (l & 1) ? a1 : a0);
#endif
}

// ---------------- workspace layout (bytes) ----------------
#define OFF_SPEX 0                              // u32 spex[2][NB][512] = 256 KB
#define OFF_OSUM (2 * NB * HIDDEN * 4)          // u32 osum[2][NB][4]  = 2 KB
#define WS_NEED  (OFF_OSUM + 2 * NB * 4 * 4)

// 256 wgs = 64 rows x 4 j-quarters; W quarter (128 KB) f16 in LDS, loaded
// straight from fp32 W_rec at init. Cross-wg exchange: SELF-CERTIFYING tagged
// words (tag<<16 | f16) with relaxed agent atomics -> exactly one L3 round
// trip per step, no flags/acks. Parity double-buffered; output pipelined one
// step so only ONE __syncthreads per step.
__global__ void __launch_bounds__(1024)
leaky_rnn_tag_kernel(const float* __restrict__ inputs,
                     const float* __restrict__ W_in,
                     const float* __restrict__ b_in,
                     const float* __restrict__ W_rec,
                     const float* __restrict__ w_out,
                     const float* __restrict__ b_out,
                     unsigned* __restrict__ spex,  // [2][NB][512]
                     unsigned* __restrict__ osum,  // [2][NB][4]
                     float* __restrict__ out /*[NB][NT][RESP]*/) {
  const int wg = blockIdx.x;
  const int r = wg & 63;   // row; quad {r, r+64, r+128, r+192} same XCD (heuristic only)
  const int q = wg >> 6;   // j-quarter
  const int t = threadIdx.x;
  const int jl = t >> 3;   // local j 0..127
  const int kq = t & 7;    // 64-wide k-eighth
  const int jg = q * 128 + jl;
  const int wave = t >> 6;
  const int lane = t & 63;

  __shared__ __align__(16) half8 ldsW8[8 * 1024];      // 128 KB: [c][t]
  // sp staging: 2 gens x 8 regions x 80 f16 (64 data + 16 pad). Region stride
  // 160B: 16B-aligned b128 reads; 8-lane same-address broadcast + <=2-way
  // bank alias (free, m136).
  __shared__ __align__(16) _Float16 spst[2][8 * 80];
  __shared__ float xin[INPUT];
  __shared__ float wsum[2][16];   // parity-indexed per-wave w_out.h partials

  // ---- init: W quarter fp32 -> f16 into LDS (one-time, ~256 KB/wg reads) ----
  {
    const float* wr = W_rec + (size_t)jg * HIDDEN + kq * 64;
#pragma unroll
    for (int c = 0; c < 8; ++c) {
      float4 x = *(const float4*)(wr + c * 8);
      float4 y = *(const float4*)(wr + c * 8 + 4);
      half8 w;
      w[0] = (_Float16)x.x; w[1] = (_Float16)x.y;
      w[2] = (_Float16)x.z; w[3] = (_Float16)x.w;
      w[4] = (_Float16)y.x; w[5] = (_Float16)y.y;
      w[6] = (_Float16)y.z; w[7] = (_Float16)y.w;
      ldsW8[c * 1024 + t] = w;
    }
  }
  if (t < INPUT) xin[t] = inputs[r * INPUT + t];
  if (t < 8 * 80) spst[0][t] = (_Float16)0.6931471805599453f;  // softplus(0)
  __syncthreads();

  float ic = b_in[jg];
  const float* wi = W_in + (size_t)jg * INPUT;
#pragma unroll
  for (int i = 0; i < INPUT; ++i) ic = fmaf(xin[i], wi[i], ic);
  const float wout = w_out[jg];
  const float bout = b_out[0];
  float h = 0.f;

  unsigned* const spex_r = spex + r * HIDDEN;   // + par*NB*HIDDEN
  unsigned* const osum_r = osum + r * 4;        // + par*NB*4
  float* const ob = out + (size_t)r * (NT * RESP);

  for (int step = 0; step < STEPS; ++step) {
    const int p = step & 1;
    const _Float16* spg = &spst[p][kq * 80];

    float a0 = 0.f, a1 = 0.f;
#pragma unroll
    for (int c = 0; c < 8; ++c)
      dot8(ldsW8[c * 1024 + t], *(const half8*)(spg + c * 8), a0, a1);
    float d = a0 + a1;
    d += __shfl_xor(d, 1);  // merge 8 k-eighths; all 8 lanes end with full d
    d += __shfl_xor(d, 2);
    d += __shfl_xor(d, 4);

    h = h * (1.f - ALPHA) + ALPHA * (d + ic);
    const float spf = fmaxf(h, 0.f) + log1pf(expf(-fabsf(h)));  // stable softplus

    if (kq == 0) {  // publish own sp: LDS (local) + tagged word (global)
      spst[1 - p][(jg >> 6) * 80 + (jg & 63)] = (_Float16)spf;
      const unsigned short hb =
          __builtin_bit_cast(unsigned short, (_Float16)spf);
      __hip_atomic_store(&spex_r[(1 - p) * NB * HIDDEN + jg],
                         ((unsigned)(step + 1) << 16) | hb,
                         __ATOMIC_RELAXED, __HIP_MEMORY_SCOPE_AGENT);
    }
    if (step >= WARM) {  // this step's projection partial -> wsum[p]
      float v = (kq == 0) ? h * wout : 0.f;
#pragma unroll
      for (int off = 32; off; off >>= 1) v += __shfl_down(v, off);
      if (lane == 0) wsum[p][wave] = v;
    }

    // ---- pipelined output for PREVIOUS step (wsum[1-p], visible since last barrier)
    if (step > WARM && wave == 15) {
      const int sprev = step - 1;
      const int pop = 1 - p;  // sprev & 1
      float own = 0.f;
      if (lane == 8) {
#pragma unroll
        for (int w = 0; w < 16; ++w) own += wsum[pop][w];
      }
      own = __shfl(own, 8);
      if (q != 0) {
        if (lane == 0) {
          const unsigned short of =
              __builtin_bit_cast(unsigned short, (_Float16)own);
          __hip_atomic_store(&osum_r[pop * NB * 4 + q],
                             ((unsigned)(sprev + 1) << 16) | of,
                             __ATOMIC_RELAXED, __HIP_MEMORY_SCOPE_AGENT);
        }
      } else {
        float pv = 0.f;
        if (lane >= 1 && lane <= 3) {
          unsigned* ad = &osum_r[pop * NB * 4 + lane];
          unsigned u; long g = 0;
          do {
            u = __hip_atomic_load(ad, __ATOMIC_RELAXED, __HIP_MEMORY_SCOPE_AGENT);
          } while ((u >> 16) != (unsigned)(sprev + 1) && ++g < (1L << 26));
          pv = (float)__builtin_bit_cast(_Float16, (unsigned short)(u & 0xffff));
        }
        const float tot = own + __shfl(pv, 1) + __shfl(pv, 2) + __shfl(pv, 3);
        const float hz = 1.f / (1.f + expf(-(bout + tot)));
        if (lane < NT) ob[lane * RESP + (sprev - WARM)] = hz;  // 8 trial copies
      }
    }

    // ---- stage 384 foreign sp for next step (poll the tagged words directly)
    if (t < 384) {
      const int k = t + (t >= q * 128 ? 128 : 0);
      unsigned* ad = &spex_r[(1 - p) * NB * HIDDEN + k];
      const unsigned want = (unsigned)(step + 1);
      unsigned u; long g = 0;
      do {
        u = __hip_atomic_load(ad, __ATOMIC_RELAXED, __HIP_MEMORY_SCOPE_AGENT);
      } while ((u >> 16) != want && ++g < (1L << 26));
      spst[1 - p][(k >> 6) * 80 + (k & 63)] =
          __builtin_bit_cast(_Float16, (unsigned short)(u & 0xffff));
    }
    __syncthreads();  // next-gen staging + wsum[p] visible
  }

  // ---- flush the final step's output (sprev = STEPS-1) ----
  if (wave == 15) {
    const int sprev = STEPS - 1;
    const int pop = sprev & 1;
    float own = 0.f;
    if (lane == 8) {
#pragma unroll
      for (int w = 0; w < 16; ++w) own += wsum[pop][w];
    }
    own = __shfl(own, 8);
    if (q != 0) {
      if (lane == 0) {
        const unsigned short of =
            __builtin_bit_cast(unsigned short, (_Float16)own);
        __hip_atomic_store(&osum_r[pop * NB * 4 + q],
                           ((unsigned)(sprev + 1) << 16) | of,
                           __ATOMIC_RELAXED, __HIP_MEMORY_SCOPE_AGENT);
      }
    } else {
      float pv = 0.f;
      if (lane >= 1 && lane <= 3) {
        unsigned* ad = &osum_r[pop * NB * 4 + lane];
        unsigned u; long g = 0;
        do {
          u = __hip_atomic_load(ad, __ATOMIC_RELAXED, __HIP_MEMORY_SCOPE_AGENT);
        } while ((u >> 16) != (unsigned)(sprev + 1) && ++g < (1L << 26));
        pv = (float)__builtin_bit_cast(_Float16, (unsigned short)(u & 0xffff));
      }
      const float tot = own + __shfl(pv, 1) + __shfl(pv, 2) + __shfl(pv, 3);
      const float hz = 1.f / (1.f + expf(-(bout + tot)));
      if (lane < NT) ob[lane * RESP + (sprev - WARM)] = hz;
    }
  }
}

// ---------------- fp32 fallback (round-0 kernel) for tiny ws ----------------
__global__ void __launch_bounds__(512, 1)
leaky_rnn_row_kernel(const float* __restrict__ inputs,
                     const float* __restrict__ W_in,
                     const float* __restrict__ b_in,
                     const float* __restrict__ W_rec,
                     const float* __restrict__ w_out,
                     const float* __restrict__ b_out,
                     float* __restrict__ out) {
  const int b = blockIdx.x;
  const int j = threadIdx.x;
  __shared__ float sp[HIDDEN];
  __shared__ float xin[INPUT];
  __shared__ float red[8];
  if (j < INPUT) xin[j] = inputs[b * INPUT + j];
  __syncthreads();
  float ic = b_in[j];
  const float* wi = W_in + j * INPUT;
#pragma unroll
  for (int i = 0; i < INPUT; ++i) ic = fmaf(xin[i], wi[i], ic);
  const float wout = w_out[j];
  const float bout = b_out[0];
  float h = 0.0f;
  sp[j] = 0.6931471805599453f;
  __syncthreads();
  const float4* __restrict__ Wr = (const float4*)(W_rec + (size_t)j * HIDDEN);
  for (int step = 0; step < STEPS; ++step) {
    float rec = 0.0f;
#pragma unroll 8
    for (int k4 = 0; k4 < HIDDEN / 4; ++k4) {
      float4 w = Wr[k4];
      float4 s = *(const float4*)&sp[4 * k4];
      rec = fmaf(w.x, s.x, rec); rec = fmaf(w.y, s.y, rec);
      rec = fmaf(w.z, s.z, rec); rec = fmaf(w.w, s.w, rec);
    }
    h = h * (1.0f - ALPHA) + ALPHA * (rec + ic);
    if (step >= WARM) {
      float v = h * wout;
#pragma unroll
      for (int off = 32; off > 0; off >>= 1) v += __shfl_down(v, off);
      if ((j & 63) == 0) red[j >> 6] = v;
    }
    __syncthreads();
    sp[j] = fmaxf(h, 0.0f) + log1pf(expf(-fabsf(h)));
    if (step >= WARM && j == 0) {
      float o = bout;
#pragma unroll
      for (int w = 0; w < 8; ++w) o += red[w];
      const float hz = 1.0f / (1.0f + expf(-o));
      float* obp = out + (size_t)b * (NT * RESP) + (step - WARM);
#pragma unroll
      for (int tr = 0; tr < NT; ++tr) obp[tr * RESP] = hz;
    }
    __syncthreads();
  }
}

extern "C" void kernel_launch(void* const* d_in, const int* in_sizes, int n_in,
                              void* d_out, int out_size, void* d_ws, size_t ws_size,
                              hipStream_t stream) {
  const float* inputs = (const float*)d_in[0];
  const float* W_in   = (const float*)d_in[1];
  const float* b_in   = (const float*)d_in[2];
  const float* W_rec  = (const float*)d_in[3];
  const float* w_out  = (const float*)d_in[4];
  const float* b_out  = (const float*)d_in[5];
  float* out = (float*)d_out;

  if (ws_size >= (size_t)WS_NEED) {
    char* ws = (char*)d_ws;
    unsigned* spex = (unsigned*)(ws + OFF_SPEX);
    unsigned* osum = (unsigned*)(ws + OFF_OSUM);
    hipMemsetAsync(ws, 0, WS_NEED, stream);  // zero tags every launch
    leaky_rnn_tag_kernel<<<dim3(256), dim3(1024), 0, stream>>>(
        inputs, W_in, b_in, W_rec, w_out, b_out, spex, osum, out);
  } else {
    leaky_rnn_row_kernel<<<dim3(NB), dim3(HIDDEN), 0, stream>>>(
        inputs, W_in, b_in, W_rec, w_out, b_out, out);
  }
}

// Round 12
// 1087.942 us; speedup vs baseline: 1.3844x; 1.3844x over previous
//
#include <hip/hip_runtime.h>
#include <math.h>

#define HIDDEN 512
#define INPUT  64
#define NB     64     // distinct batch rows (8 trials are bit-identical replicas)
#define NT     8
#define WARM   100
#define RESP   400
#define STEPS  (WARM + RESP)
#define ALPHA  0.1f

#define NREGC  23     // half8 chunks per thread pinned in VGPRs (92 VGPRs)
#define NLDSC  9      // half8 chunks per thread in LDS (144 KB)

typedef _Float16 half8  __attribute__((ext_vector_type(8)));
typedef _Float16 half2v __attribute__((ext_vector_type(2)));

#if defined(__has_builtin)
#  if __has_builtin(__builtin_amdgcn_fdot2)
#    define HAS_FDOT2 1
#  endif
#endif

// Direct register-count directive — the one allocator knob not yet tried.
// Guarded: unsupported toolchain just compiles without it (R4 behavior).
#if defined(__has_attribute)
#  if __has_attribute(amdgpu_num_vgpr)
#    define VGPR128 __attribute__((amdgpu_num_vgpr(128)))
#  endif
#endif
#ifndef VGPR128
#  define VGPR128
#endif

__device__ __forceinline__ void dot8(half8 w, half8 s, float& a0, float& a1) {
#ifdef HAS_FDOT2
  a0 = __builtin_amdgcn_fdot2(__builtin_shufflevector(w, w, 0, 1),
                              __builtin_shufflevector(s, s, 0, 1), a0, false);
  a1 = __builtin_amdgcn_fdot2(__builtin_shufflevector(w, w, 2, 3),
                              __builtin_shufflevector(s, s, 2, 3), a1, false);
  a0 = __builtin_amdgcn_fdot2(__builtin_shufflevector(w, w, 4, 5),
                              __builtin_shufflevector(s, s, 4, 5), a0, false);
  a1 = __builtin_amdgcn_fdot2(__builtin_shufflevector(w, w, 6, 7),
                              __builtin_shufflevector(s, s, 6, 7), a1, false);
#else
#pragma unroll
  for (int l = 0; l < 8; ++l)
    ((l & 1) ? a1 : a0) = fmaf((float)w[l], (float)s[l], (l & 1) ? a1 : a0);
#endif
}

// w chunk supplied as 4 opaque floats (each = 2 packed f16)
__device__ __forceinline__ void dot8f(float w0, float w1, float w2, float w3,
                                      half8 s, float& a0, float& a1) {
#ifdef HAS_FDOT2
  a0 = __builtin_amdgcn_fdot2(__builtin_bit_cast(half2v, w0),
                              __builtin_shufflevector(s, s, 0, 1), a0, false);
  a1 = __builtin_amdgcn_fdot2(__builtin_bit_cast(half2v, w1),
                              __builtin_shufflevector(s, s, 2, 3), a1, false);
  a0 = __builtin_amdgcn_fdot2(__builtin_bit_cast(half2v, w2),
                              __builtin_shufflevector(s, s, 4, 5), a0, false);
  a1 = __builtin_amdgcn_fdot2(__builtin_bit_cast(half2v, w3),
                              __builtin_shufflevector(s, s, 6, 7), a1, false);
#else
  const float wf[4] = {w0, w1, w2, w3};
#pragma unroll
  for (int p = 0; p < 4; ++p) {
    half2v wp = __builtin_bit_cast(half2v, wf[p]);
    float& a = (p & 1) ? a1 : a0;
    a = fmaf((float)wp[0], (float)s[2 * p], a);
    a = fmaf((float)wp[1], (float)s[2 * p + 1], a);
  }
#endif
}

// Pack W_rec fp32 [j][k] -> f16 Wpk[k>>3][j][8] (coalesced main-kernel loads).
__global__ void convert_w_pack_kernel(const float* __restrict__ W,
                                      _Float16* __restrict__ Wpk) {
  const int t = blockIdx.x * blockDim.x + threadIdx.x;  // HIDDEN*64 threads
  const int kblk = t & 63;
  const int j = t >> 6;
  const float* src = W + (size_t)j * HIDDEN + kblk * 8;
  _Float16* dst = Wpk + ((size_t)kblk * HIDDEN + j) * 8;
#pragma unroll
  for (int l = 0; l < 8; ++l) dst[l] = (_Float16)src[l];
}

// One wg per distinct batch row; 1024 threads = 2 k-halves x 512 j.
// W CU-resident: 23/32 chunks pinned in VGPRs (asm pin blocks remat),
// 9/32 in LDS. HW allows 128 regs/wave at 4 waves/SIMD (proven by R10's
// 64V+64A launch); amdgpu_num_vgpr(128) asks the allocator for it directly.
__global__ void VGPR128
__attribute__((amdgpu_flat_work_group_size(1024, 1024), amdgpu_waves_per_eu(4, 4)))
leaky_rnn_res_kernel(const float* __restrict__ inputs,
                     const float* __restrict__ W_in,
                     const float* __restrict__ b_in,
                     const _Float16* __restrict__ Wpk,
                     const float* __restrict__ w_out,
                     const float* __restrict__ b_out,
                     float* __restrict__ out /*[NB][NT][RESP]*/) {
  const int b = blockIdx.x;
  const int t = threadIdx.x;
  const int j = t & (HIDDEN - 1);
  const int kh = t >> 9;  // 0 or 1

  __shared__ __align__(16) half8 ldsW[NLDSC][1024];   // 144 KB, chunk-major
  __shared__ __align__(16) _Float16 sp_h[HIDDEN];     // softplus(h) as f16
  __shared__ float xin[INPUT];
  __shared__ float redk[HIDDEN];  // upper-k-half partial dots
  __shared__ float wsum[8];       // per-wave w_out.h partials

  const half8* __restrict__ Wp8 =
      (const half8*)Wpk + (size_t)(kh * 32) * HIDDEN + j;
  const float4* __restrict__ Wp4 = (const float4*)Wp8;  // same addresses

  // ---- init: W into regs + LDS (coalesced: lanes 16B apart) ----
  float wrf[NREGC * 4];
#pragma unroll
  for (int c = 0; c < NREGC; ++c) {
    float4 v = Wp4[(size_t)c * HIDDEN];
    wrf[4 * c + 0] = v.x;
    wrf[4 * c + 1] = v.y;
    wrf[4 * c + 2] = v.z;
    wrf[4 * c + 3] = v.w;
    // Opaque producer: values cannot be rematerialized from memory.
    asm volatile("" : "+v"(wrf[4 * c + 0]), "+v"(wrf[4 * c + 1]),
                      "+v"(wrf[4 * c + 2]), "+v"(wrf[4 * c + 3]));
  }
#pragma unroll
  for (int c = 0; c < NLDSC; ++c) ldsW[c][t] = Wp8[(size_t)(NREGC + c) * HIDDEN];

  if (t < INPUT) xin[t] = inputs[b * INPUT + t];
  __syncthreads();  // xin + ldsW visible

  float ic = 0.f, wout = 0.f;
  const float bout = b_out[0];
  if (t < HIDDEN) {
    ic = b_in[j];
    const float* wi = W_in + (size_t)j * INPUT;
#pragma unroll
    for (int i = 0; i < INPUT; ++i) ic = fmaf(xin[i], wi[i], ic);
    wout = w_out[j];
    sp_h[j] = (_Float16)0.6931471805599453f;  // softplus(0)
  }
  float h = 0.f;
  __syncthreads();  // sp_h visible

  const half8* sp8 = ((const half8*)sp_h) + kh * 32;
  float* const ob = out + (size_t)b * (NT * RESP) + (t < NT ? t * RESP : 0);

  for (int step = 0; step < STEPS; ++step) {
    float a0 = 0.f, a1 = 0.f;
    // LDS-resident chunks first (ds reads overlap reg-chunk VALU)
#pragma unroll
    for (int c = 0; c < NLDSC; ++c)
      dot8(ldsW[c][t], sp8[NREGC + c], a0, a1);
    // register-pinned chunks
#pragma unroll
    for (int c = 0; c < NREGC; ++c)
      dot8f(wrf[4 * c + 0], wrf[4 * c + 1], wrf[4 * c + 2], wrf[4 * c + 3],
            sp8[c], a0, a1);
    const float acc = a0 + a1;

    if (t >= HIDDEN) redk[j] = acc;  // upper k-half publishes partial
    __syncthreads();                 // redk ready; sp_h reads complete

    if (t < HIDDEN) {
      const float rec = acc + redk[j];
      h = h * (1.f - ALPHA) + ALPHA * (rec + ic);
      const float sp = fmaxf(h, 0.f) + log1pf(expf(-fabsf(h)));  // stable softplus
      sp_h[j] = (_Float16)sp;
      if (step >= WARM) {
        float v = h * wout;
#pragma unroll
        for (int off = 32; off > 0; off >>= 1) v += __shfl_down(v, off);
        if ((t & 63) == 0) wsum[t >> 6] = v;
      }
    }
    __syncthreads();  // new sp_h + wsum visible

    if (step >= WARM && t < NT) {
      float o = bout;
#pragma unroll
      for (int w = 0; w < 8; ++w) o += wsum[w];
      const float hz = 1.f / (1.f + expf(-o));
      ob[step - WARM] = hz;  // 8 identical trial copies, one lane each
    }
  }
}

// ---------------- fp32 fallback (round-0 kernel) for tiny ws ----------------
__global__ void __launch_bounds__(512, 1)
leaky_rnn_row_kernel(const float* __restrict__ inputs,
                     const float* __restrict__ W_in,
                     const float* __restrict__ b_in,
                     const float* __restrict__ W_rec,
                     const float* __restrict__ w_out,
                     const float* __restrict__ b_out,
                     float* __restrict__ out) {
  const int b = blockIdx.x;
  const int j = threadIdx.x;
  __shared__ float sp[HIDDEN];
  __shared__ float xin[INPUT];
  __shared__ float red[8];
  if (j < INPUT) xin[j] = inputs[b * INPUT + j];
  __syncthreads();
  float ic = b_in[j];
  const float* wi = W_in + j * INPUT;
#pragma unroll
  for (int i = 0; i < INPUT; ++i) ic = fmaf(xin[i], wi[i], ic);
  const float wout = w_out[j];
  const float bout = b_out[0];
  float h = 0.0f;
  sp[j] = 0.6931471805599453f;
  __syncthreads();
  const float4* __restrict__ Wr = (const float4*)(W_rec + (size_t)j * HIDDEN);
  for (int step = 0; step < STEPS; ++step) {
    float rec = 0.0f;
#pragma unroll 8
    for (int k4 = 0; k4 < HIDDEN / 4; ++k4) {
      float4 w = Wr[k4];
      float4 s = *(const float4*)&sp[4 * k4];
      rec = fmaf(w.x, s.x, rec); rec = fmaf(w.y, s.y, rec);
      rec = fmaf(w.z, s.z, rec); rec = fmaf(w.w, s.w, rec);
    }
    h = h * (1.0f - ALPHA) + ALPHA * (rec + ic);
    if (step >= WARM) {
      float v = h * wout;
#pragma unroll
      for (int off = 32; off > 0; off >>= 1) v += __shfl_down(v, off);
      if ((j & 63) == 0) red[j >> 6] = v;
    }
    __syncthreads();
    sp[j] = fmaxf(h, 0.0f) + log1pf(expf(-fabsf(h)));
    if (step >= WARM && j == 0) {
      float o = bout;
#pragma unroll
      for (int w = 0; w < 8; ++w) o += red[w];
      const float hz = 1.0f / (1.0f + expf(-o));
      float* obp = out + (size_t)b * (NT * RESP) + (step - WARM);
#pragma unroll
      for (int tr = 0; tr < NT; ++tr) obp[tr * RESP] = hz;
    }
    __syncthreads();
  }
}

extern "C" void kernel_launch(void* const* d_in, const int* in_sizes, int n_in,
                              void* d_out, int out_size, void* d_ws, size_t ws_size,
                              hipStream_t stream) {
  const float* inputs = (const float*)d_in[0];
  const float* W_in   = (const float*)d_in[1];
  const float* b_in   = (const float*)d_in[2];
  const float* W_rec  = (const float*)d_in[3];
  const float* w_out  = (const float*)d_in[4];
  const float* b_out  = (const float*)d_in[5];
  float* out = (float*)d_out;

  const int nW = HIDDEN * HIDDEN;
  if (ws_size >= (size_t)nW * sizeof(_Float16)) {
    _Float16* Wpk = (_Float16*)d_ws;
    convert_w_pack_kernel<<<dim3(HIDDEN * 64 / 256), dim3(256), 0, stream>>>(W_rec, Wpk);
    leaky_rnn_res_kernel<<<dim3(NB), dim3(2 * HIDDEN), 0, stream>>>(
        inputs, W_in, b_in, Wpk, w_out, b_out, out);
  } else {
    leaky_rnn_row_kernel<<<dim3(NB), dim3(HIDDEN), 0, stream>>>(
        inputs, W_in, b_in, W_rec, w_out, b_out, out);
  }
}